// Round 8
// baseline (252.437 us; speedup 1.0000x reference)
//
#include <hip/hip_runtime.h>
#include <hip/hip_bf16.h>
#include <cstdint>
#include <cstddef>

#define N_ATOMS 10000
#define NSTRUCT 100
#define NP 4
#define NS 4
#define NF2 2560      // 4 l x 640 block-aligned symmetric-packed features
#define HID 256
#define APAD 10240

// prep-kernel block ranges
#define PB_FEAT  2500                     // [0,2500): power spectrum, 4 atoms/block
#define PB_W0    (PB_FEAT + 2560)         // w0cvt: 8(n) x 80(k) x 4(p)
#define PB_W1    (PB_W0 + 256)            // w1cvt: 8 x 8 x 4
#define PB_ZERO  (PB_W1 + 300)            // fh tail rows 10000..10239
#define PB_TOTAL (PB_ZERO + 1)            // + out zero

typedef __attribute__((ext_vector_type(8))) _Float16 f16x8;
typedef __attribute__((ext_vector_type(8))) ushort u16x8;
typedef __attribute__((ext_vector_type(4))) float f32x4;

__device__ __forceinline__ float silu(float x) {
  return x / (1.f + __expf(-x));
}
__device__ __forceinline__ ushort f2h(float x) {
  _Float16 h = (_Float16)x;
  return *reinterpret_cast<ushort*>(&h);
}
// chunk c in [0,80) -> (row q, r-block b). Row q owns blocks q>>3 .. 3.
__device__ __forceinline__ void cdec(int c, int& q, int& b) {
  if (c < 32)      { q = c >> 2; b = c & 3; }
  else if (c < 56) { int x = c - 32; int j = (x * 171) >> 9; q = 8 + j; b = 1 + (x - j * 3); }
  else if (c < 72) { int x = c - 56; q = 16 + (x >> 1); b = 2 + (x & 1); }
  else             { q = 24 + (c - 72); b = 3; }
}

typedef __attribute__((address_space(3))) uint32_t lds_u32;
typedef const __attribute__((address_space(1))) uint32_t glb_u32;
__device__ __forceinline__ void glds16(const ushort* g, ushort* l) {
  __builtin_amdgcn_global_load_lds((glb_u32*)g, (lds_u32*)l, 16, 0, 0);
}

// ---------------- Kernel P: fused prep (round-4 verbatim) ------------------
__global__ __launch_bounds__(256) void prep_kernel(
    const float* __restrict__ c0, const float* __restrict__ c1,
    const float* __restrict__ c2, const float* __restrict__ c3,
    const float* __restrict__ W0, const float* __restrict__ W1,
    ushort* __restrict__ fh, ushort* __restrict__ W0t,
    ushort* __restrict__ W1t, float* __restrict__ out) {
  __shared__ float shbuf[2048];   // feat: 4 waves x 512; cvt: 32x33
  int b = blockIdx.x;
  int tid = threadIdx.x;

  if (b < PB_FEAT) {
    // ---- power spectrum, one WAVE per atom, 5 chunks/lane ----
    int wv = tid >> 6, lane = tid & 63;
    int a = b * 4 + wv;
    float* cs = shbuf + wv * 512;
    for (int i = 0; i < 8; ++i) {
      int e = lane + i * 64;
      float v;
      if (e < 32)       v = c0[a * 32  + e];
      else if (e < 128) v = c1[a * 96  + (e - 32)];
      else if (e < 288) v = c2[a * 160 + (e - 128)];
      else              v = c3[a * 224 + (e - 288)];
      cs[e] = v;
    }
    __syncthreads();
    const float cg[4]  = {1.0f, 0.5773502691896258f, 0.4472135954999579f, 0.3779644730092272f};
    const int  off[4]  = {0, 32, 128, 288};
    const int  nm[4]   = {1, 3, 5, 7};
#pragma unroll
    for (int t = 0; t < 5; ++t) {
      int cc = lane + t * 64;           // [0,320), all lanes busy
      int l = cc / 80, c = cc - l * 80;
      int q, bb; cdec(c, q, bb);
      int rb = bb * 8;
      const float* base = cs + off[l];
      float s[8] = {0.f, 0.f, 0.f, 0.f, 0.f, 0.f, 0.f, 0.f};
      for (int m = 0; m < nm[l]; ++m) {
        float bq = base[m * 32 + q];
        float4 v0 = *reinterpret_cast<const float4*>(&base[m * 32 + rb]);
        float4 v1 = *reinterpret_cast<const float4*>(&base[m * 32 + rb + 4]);
        s[0] += bq * v0.x; s[1] += bq * v0.y; s[2] += bq * v0.z; s[3] += bq * v0.w;
        s[4] += bq * v1.x; s[5] += bq * v1.y; s[6] += bq * v1.z; s[7] += bq * v1.w;
      }
      u16x8 o;
#pragma unroll
      for (int u = 0; u < 8; ++u) o[u] = f2h(s[u] * cg[l]);
      *reinterpret_cast<u16x8*>(&fh[(size_t)a * NF2 + cc * 8]) = o;
    }
  } else if (b < PB_W0) {
    // ---- W0' fold -> W0t [p][h][fk] fp16 ----
    int idx = b - PB_FEAT;
    int nx = idx & 7;
    int rest = idx >> 3;
    int ky = rest % 80, p = rest / 80;
    int kt = ky * 32, nt = nx * 32;
    int lx = tid & 31, ly = tid >> 5;
    float (*t)[33] = (float(*)[33])shbuf;
    const float* src = W0 + (size_t)p * 4096 * HID;
#pragma unroll
    for (int i = 0; i < 4; ++i) {
      int kf = kt + ly + i * 8;
      int l = kf / 640, w = kf - l * 640;
      int c = w >> 3, s = w & 7;
      int q, bb; cdec(c, q, bb);
      int r = bb * 8 + s;
      float v = 0.f;
      if (r >= q) {
        v = src[(size_t)(l * 1024 + q * 32 + r) * HID + nt + lx];
        if (r > q) v += src[(size_t)(l * 1024 + r * 32 + q) * HID + nt + lx];
      }
      t[ly + i * 8][lx] = v;
    }
    __syncthreads();
    ushort* dst = W0t + (size_t)p * HID * NF2;
#pragma unroll
    for (int i = 0; i < 4; ++i)
      dst[(size_t)(nt + ly + i * 8) * NF2 + kt + lx] = f2h(t[lx][ly + i * 8]);
  } else if (b < PB_W1) {
    int idx = b - PB_W0;
    int nx = idx & 7, ky = (idx >> 3) & 7, p = idx >> 6;
    int kt = ky * 32, nt = nx * 32;
    int lx = tid & 31, ly = tid >> 5;
    float (*t)[33] = (float(*)[33])shbuf;
    const float* src = W1 + (size_t)p * HID * HID;
#pragma unroll
    for (int i = 0; i < 4; ++i)
      t[ly + i * 8][lx] = src[(size_t)(kt + ly + i * 8) * HID + nt + lx];
    __syncthreads();
    ushort* dst = W1t + (size_t)p * HID * HID;
#pragma unroll
    for (int i = 0; i < 4; ++i)
      dst[(size_t)(nt + ly + i * 8) * HID + kt + lx] = f2h(t[lx][ly + i * 8]);
  } else if (b < PB_ZERO) {
    int idx = b - PB_W1;
    size_t e = (size_t)idx * 2048 + tid * 8;
    u16x8 z = (u16x8){0, 0, 0, 0, 0, 0, 0, 0};
    *reinterpret_cast<u16x8*>(&fh[(size_t)N_ATOMS * NF2 + e]) = z;
  } else {
    if (tid < NSTRUCT) out[tid] = 0.f;
  }
}

// ---------------- Kernel F: FUSED gemm0 + mlp1 -----------------------------
// Phase 1: 64m x 256n (one full p) per block, BK=32, round-0 2-barrier loop,
//   4 waves split n (wn = wid*64). A: 32 LDS-row paired layout (4KB);
//   B: 128 LDS-row paired layout (16KB). silu(pw*acc) -> LDS (mlp1 layout).
// Phase 2: mlp1 body verbatim on the in-LDS h0 (64x256), layer-2 + sorted-
//   sid run-length segment sum. h0f HBM round-trip eliminated.
__global__ __launch_bounds__(256) void gemm_fused(
    const ushort* __restrict__ fh, const ushort* __restrict__ W0t,
    const float* __restrict__ combW, const int* __restrict__ species,
    const ushort* __restrict__ W1t, const float* __restrict__ W2,
    const int* __restrict__ sid, float* __restrict__ out) {
  __shared__ ushort sh[16384];      // phase1: A[0,2048) B[2048,10240); phase2: h0 64x256
  __shared__ float sout[NSTRUCT];
  int tid = threadIdx.x;
  int linear = blockIdx.x;                   // 0..639 (mlp1's proven mapping)
  int xc = linear & 7, s = linear >> 3;
  int p = s & 3, t = s >> 2;
  int bm = ((t >> 1) * 8 + xc) * 128 + (t & 1) * 64;   // 64-row m-tile
  int wid = tid >> 6, lane = tid & 63;
  int wn = wid * 64;                         // wave's n-quarter of p's 256

  if (tid < NSTRUCT) sout[tid] = 0.f;

  int mrow = lane & 15, qv = lane >> 4, h7 = mrow & 7;

  // ---- A staging (one 16B unit/thread): 32 LDS rows x 8 phys chunks ----
  {
  }
  int prA = tid >> 3, pcA_ = tid & 7;
  int lgA = pcA_ ^ (prA & 7);
  const ushort* gA = fh + (size_t)(bm + prA + 32 * (lgA >> 2)) * NF2 + (lgA & 3) * 8;
  ushort* lA = sh + tid * 8;
  // ---- B staging (4 units/thread): 128 LDS rows x 8 phys chunks ----
  int prB = tid >> 3, pcB_ = tid & 7;
  int lgB = pcB_ ^ (prB & 7);          // same for all 4 units (pr&7 invariant)
  int mhB = lgB >> 2, kcB = lgB & 3;
  const ushort* wp = W0t + (size_t)p * HID * NF2;
  const ushort* gB0 = wp + (size_t)(prB +  0 + 128 * mhB) * NF2 + kcB * 8;
  const ushort* gB1 = wp + (size_t)(prB + 32 + 128 * mhB) * NF2 + kcB * 8;
  const ushort* gB2 = wp + (size_t)(prB + 64 + 128 * mhB) * NF2 + kcB * 8;
  const ushort* gB3 = wp + (size_t)(prB + 96 + 128 * mhB) * NF2 + kcB * 8;
  ushort* lB = sh + 2048 + tid * 8;

  f32x4 acc[4][4];
#pragma unroll
  for (int i = 0; i < 4; ++i)
#pragma unroll
    for (int j = 0; j < 4; ++j) acc[i][j] = (f32x4){0.f, 0.f, 0.f, 0.f};

  int pcB = ((wid >> 1) * 4 + qv) ^ h7;              // wave-const B phys chunk
  int browb = (wid & 1) * 64;                        // B LDS row base

  for (int k0 = 0; k0 < NF2; k0 += 32) {
    glds16(gA  + k0, lA);
    glds16(gB0 + k0, lB);
    glds16(gB1 + k0, lB + 2048);
    glds16(gB2 + k0, lB + 4096);
    glds16(gB3 + k0, lB + 6144);
    __syncthreads();

    f16x8 af[4], bf[4];
#pragma unroll
    for (int i = 0; i < 4; ++i) {
      int pca = ((i >> 1) * 4 + qv) ^ h7;
      af[i] = *reinterpret_cast<const f16x8*>(&sh[((i & 1) * 16 + mrow) * 64 + pca * 8]);
    }
#pragma unroll
    for (int j = 0; j < 4; ++j)
      bf[j] = *reinterpret_cast<const f16x8*>(&sh[2048 + (browb + j * 16 + mrow) * 64 + pcB * 8]);
#pragma unroll
    for (int i = 0; i < 4; ++i)
#pragma unroll
      for (int j = 0; j < 4; ++j)
        acc[i][j] = __builtin_amdgcn_mfma_f32_16x16x32_f16(af[i], bf[j], acc[i][j], 0, 0, 0);
    __syncthreads();
  }

  // ---- phase-1 epilogue: silu(pw*acc) -> LDS h0 (mlp1 swizzled layout) ----
  int col = lane & 15, quad = lane >> 4;
#pragma unroll
  for (int i = 0; i < 4; ++i) {
#pragma unroll
    for (int r = 0; r < 4; ++r) {
      int mloc = i * 16 + quad * 4 + r;
      int m = bm + mloc;
      bool live = (m < N_ATOMS);
      float pw = live ? combW[p * NS + species[m]] : 0.f;
#pragma unroll
      for (int j = 0; j < 4; ++j) {
        int h = wn + j * 16 + col;
        float v = live ? silu(pw * acc[i][j][r]) : 0.f;
        sh[mloc * 256 + (((h >> 3) ^ (mloc & 7)) << 3) + (h & 7)] = f2h(v);
      }
    }
  }
  __syncthreads();

  // ---- phase 2: mlp1 body on in-LDS h0 ----
  const ushort* wb = W1t + (size_t)p * HID * HID;
  const ushort* wrow[4];
#pragma unroll
  for (int j = 0; j < 4; ++j)
    wrow[j] = wb + (size_t)(wn + j * 16 + mrow) * 256 + qv * 8;

  f16x8 bc[4], bn_[4];
#pragma unroll
  for (int j = 0; j < 4; ++j) bc[j] = *reinterpret_cast<const f16x8*>(wrow[j]);

  f32x4 acc2[4][4];
#pragma unroll
  for (int i = 0; i < 4; ++i)
#pragma unroll
    for (int j = 0; j < 4; ++j) acc2[i][j] = (f32x4){0.f, 0.f, 0.f, 0.f};

#pragma unroll
  for (int ki = 0; ki < 8; ++ki) {
    if (ki < 7) {
#pragma unroll
      for (int j = 0; j < 4; ++j)
        bn_[j] = *reinterpret_cast<const f16x8*>(wrow[j] + (ki + 1) * 32);
    }
    f16x8 af[4];
#pragma unroll
    for (int i = 0; i < 4; ++i) {
      int row = i * 16 + mrow;
      int pc2 = (ki * 4 + qv) ^ h7;
      af[i] = *reinterpret_cast<const f16x8*>(&sh[row * 256 + pc2 * 8]);
    }
#pragma unroll
    for (int i = 0; i < 4; ++i)
#pragma unroll
      for (int j = 0; j < 4; ++j)
        acc2[i][j] = __builtin_amdgcn_mfma_f32_16x16x32_f16(af[i], bc[j], acc2[i][j], 0, 0, 0);
    if (ki < 7) {
#pragma unroll
      for (int j = 0; j < 4; ++j) bc[j] = bn_[j];
    }
  }

  // layer-2 + sorted-sid run-length segment sum (round-4 verified)
  float w2j[4];
#pragma unroll
  for (int j = 0; j < 4; ++j) w2j[j] = W2[p * 256 + wn + j * 16 + col];
  float runv = 0.f;
  int runs = -1;
#pragma unroll
  for (int i = 0; i < 4; ++i) {
#pragma unroll
    for (int r = 0; r < 4; ++r) {
      float v = silu(acc2[i][0][r]) * w2j[0] + silu(acc2[i][1][r]) * w2j[1]
              + silu(acc2[i][2][r]) * w2j[2] + silu(acc2[i][3][r]) * w2j[3];
      v += __shfl_xor(v, 1, 64);
      v += __shfl_xor(v, 2, 64);
      v += __shfl_xor(v, 4, 64);
      v += __shfl_xor(v, 8, 64);
      if (col == 0) {
        int m = bm + i * 16 + quad * 4 + r;       // strictly increasing
        int s_ = (m < N_ATOMS) ? sid[m] : -1;     // sorted, non-decreasing
        if (s_ != runs) {
          if (runs >= 0) atomicAdd(&sout[runs], runv);
          runs = s_;
          runv = 0.f;
        }
        if (s_ >= 0) runv += v;
      }
    }
  }
  if (col == 0 && runs >= 0) atomicAdd(&sout[runs], runv);

  __syncthreads();
  if (tid < NSTRUCT) {
    float v = sout[tid];
    if (v != 0.f) atomicAdd(&out[tid], v);
  }
}

extern "C" void kernel_launch(void* const* d_in, const int* in_sizes, int n_in,
                              void* d_out, int out_size, void* d_ws, size_t ws_size,
                              hipStream_t stream) {
  const float* c0      = (const float*)d_in[0];
  const float* c1      = (const float*)d_in[1];
  const float* c2      = (const float*)d_in[2];
  const float* c3      = (const float*)d_in[3];
  const int*   species = (const int*)d_in[4];
  const int*   sid     = (const int*)d_in[5];
  const float* combW   = (const float*)d_in[6];
  const float* W0      = (const float*)d_in[7];
  const float* W1      = (const float*)d_in[8];
  const float* W2      = (const float*)d_in[9];
  float*       out     = (float*)d_out;

  // ws: fh 52.4MB | W0t 5.2MB | W1t 0.5MB  (h0f eliminated by fusion)
  ushort* fh  = (ushort*)d_ws;
  ushort* W0t = fh  + (size_t)APAD * NF2;
  ushort* W1t = W0t + (size_t)NP * HID * NF2;

  prep_kernel<<<PB_TOTAL, 256, 0, stream>>>(c0, c1, c2, c3, W0, W1,
                                            fh, W0t, W1t, out);

  gemm_fused<<<640, 256, 0, stream>>>(fh, W0t, combW, species,
                                      W1t, W2, sid, out);
}

// Round 9
// 222.827 us; speedup vs baseline: 1.1329x; 1.1329x over previous
//
#include <hip/hip_runtime.h>
#include <hip/hip_bf16.h>
#include <cstdint>
#include <cstddef>

#define N_ATOMS 10000
#define NSTRUCT 100
#define NP 4
#define NS 4
#define NF2 2560      // 4 l x 640 block-aligned symmetric-packed features
#define HID 256
#define APAD 10240    // 80 tiles of 128

// prep-kernel block ranges
#define PB_FEAT  2500                     // [0,2500): power spectrum, 4 atoms/block
#define PB_W0    (PB_FEAT + 2560)         // w0cvt: 8(n) x 80(k) x 4(p)
#define PB_W1    (PB_W0 + 256)            // w1cvt: 8 x 8 x 4
#define PB_ZERO  (PB_W1 + 300)            // fh tail rows 10000..10239
#define PB_TOTAL (PB_ZERO + 1)            // + out zero

typedef __attribute__((ext_vector_type(8))) _Float16 f16x8;
typedef __attribute__((ext_vector_type(8))) ushort u16x8;
typedef __attribute__((ext_vector_type(4))) float f32x4;

__device__ __forceinline__ float silu(float x) {
  return x / (1.f + __expf(-x));
}
__device__ __forceinline__ ushort f2h(float x) {
  _Float16 h = (_Float16)x;
  return *reinterpret_cast<ushort*>(&h);
}
// chunk c in [0,80) -> (row q, r-block b). Row q owns blocks q>>3 .. 3.
__device__ __forceinline__ void cdec(int c, int& q, int& b) {
  if (c < 32)      { q = c >> 2; b = c & 3; }
  else if (c < 56) { int x = c - 32; int j = (x * 171) >> 9; q = 8 + j; b = 1 + (x - j * 3); }
  else if (c < 72) { int x = c - 56; q = 16 + (x >> 1); b = 2 + (x & 1); }
  else             { q = 24 + (c - 72); b = 3; }
}

typedef __attribute__((address_space(3))) uint32_t lds_u32;
typedef const __attribute__((address_space(1))) uint32_t glb_u32;
__device__ __forceinline__ void glds16(const ushort* g, ushort* l) {
  __builtin_amdgcn_global_load_lds((glb_u32*)g, (lds_u32*)l, 16, 0, 0);
}

// ---------------- Kernel P: fused prep (round-4 verbatim) ------------------
__global__ __launch_bounds__(256) void prep_kernel(
    const float* __restrict__ c0, const float* __restrict__ c1,
    const float* __restrict__ c2, const float* __restrict__ c3,
    const float* __restrict__ W0, const float* __restrict__ W1,
    ushort* __restrict__ fh, ushort* __restrict__ W0t,
    ushort* __restrict__ W1t, float* __restrict__ out) {
  __shared__ float shbuf[2048];   // feat: 4 waves x 512; cvt: 32x33
  int b = blockIdx.x;
  int tid = threadIdx.x;

  if (b < PB_FEAT) {
    // ---- power spectrum, one WAVE per atom, 5 chunks/lane ----
    int wv = tid >> 6, lane = tid & 63;
    int a = b * 4 + wv;
    float* cs = shbuf + wv * 512;
    for (int i = 0; i < 8; ++i) {
      int e = lane + i * 64;
      float v;
      if (e < 32)       v = c0[a * 32  + e];
      else if (e < 128) v = c1[a * 96  + (e - 32)];
      else if (e < 288) v = c2[a * 160 + (e - 128)];
      else              v = c3[a * 224 + (e - 288)];
      cs[e] = v;
    }
    __syncthreads();
    const float cg[4]  = {1.0f, 0.5773502691896258f, 0.4472135954999579f, 0.3779644730092272f};
    const int  off[4]  = {0, 32, 128, 288};
    const int  nm[4]   = {1, 3, 5, 7};
#pragma unroll
    for (int t = 0; t < 5; ++t) {
      int cc = lane + t * 64;           // [0,320), all lanes busy
      int l = cc / 80, c = cc - l * 80;
      int q, bb; cdec(c, q, bb);
      int rb = bb * 8;
      const float* base = cs + off[l];
      float s[8] = {0.f, 0.f, 0.f, 0.f, 0.f, 0.f, 0.f, 0.f};
      for (int m = 0; m < nm[l]; ++m) {
        float bq = base[m * 32 + q];
        float4 v0 = *reinterpret_cast<const float4*>(&base[m * 32 + rb]);
        float4 v1 = *reinterpret_cast<const float4*>(&base[m * 32 + rb + 4]);
        s[0] += bq * v0.x; s[1] += bq * v0.y; s[2] += bq * v0.z; s[3] += bq * v0.w;
        s[4] += bq * v1.x; s[5] += bq * v1.y; s[6] += bq * v1.z; s[7] += bq * v1.w;
      }
      u16x8 o;
#pragma unroll
      for (int u = 0; u < 8; ++u) o[u] = f2h(s[u] * cg[l]);
      *reinterpret_cast<u16x8*>(&fh[(size_t)a * NF2 + cc * 8]) = o;
    }
  } else if (b < PB_W0) {
    // ---- W0' fold -> W0t [p][h][fk] fp16 ----
    int idx = b - PB_FEAT;
    int nx = idx & 7;
    int rest = idx >> 3;
    int ky = rest % 80, p = rest / 80;
    int kt = ky * 32, nt = nx * 32;
    int lx = tid & 31, ly = tid >> 5;
    float (*t)[33] = (float(*)[33])shbuf;
    const float* src = W0 + (size_t)p * 4096 * HID;
#pragma unroll
    for (int i = 0; i < 4; ++i) {
      int kf = kt + ly + i * 8;
      int l = kf / 640, w = kf - l * 640;
      int c = w >> 3, s = w & 7;
      int q, bb; cdec(c, q, bb);
      int r = bb * 8 + s;
      float v = 0.f;
      if (r >= q) {
        v = src[(size_t)(l * 1024 + q * 32 + r) * HID + nt + lx];
        if (r > q) v += src[(size_t)(l * 1024 + r * 32 + q) * HID + nt + lx];
      }
      t[ly + i * 8][lx] = v;
    }
    __syncthreads();
    ushort* dst = W0t + (size_t)p * HID * NF2;
#pragma unroll
    for (int i = 0; i < 4; ++i)
      dst[(size_t)(nt + ly + i * 8) * NF2 + kt + lx] = f2h(t[lx][ly + i * 8]);
  } else if (b < PB_W1) {
    int idx = b - PB_W0;
    int nx = idx & 7, ky = (idx >> 3) & 7, p = idx >> 6;
    int kt = ky * 32, nt = nx * 32;
    int lx = tid & 31, ly = tid >> 5;
    float (*t)[33] = (float(*)[33])shbuf;
    const float* src = W1 + (size_t)p * HID * HID;
#pragma unroll
    for (int i = 0; i < 4; ++i)
      t[ly + i * 8][lx] = src[(size_t)(kt + ly + i * 8) * HID + nt + lx];
    __syncthreads();
    ushort* dst = W1t + (size_t)p * HID * HID;
#pragma unroll
    for (int i = 0; i < 4; ++i)
      dst[(size_t)(nt + ly + i * 8) * HID + kt + lx] = f2h(t[lx][ly + i * 8]);
  } else if (b < PB_ZERO) {
    int idx = b - PB_W1;
    size_t e = (size_t)idx * 2048 + tid * 8;
    u16x8 z = (u16x8){0, 0, 0, 0, 0, 0, 0, 0};
    *reinterpret_cast<u16x8*>(&fh[(size_t)N_ATOMS * NF2 + e]) = z;
  } else {
    if (tid < NSTRUCT) out[tid] = 0.f;
  }
}

// ---------------- Kernel B: fp16 MFMA GEMM0, 128x128, BK=64, single buffer -
// Same 2-barrier structure as the 82.6us round-0 champion; only change is
// BK 32->64 (40 steps x 32 MFMA instead of 80 x 16) to halve the number of
// barrier-drain stalls. 32KB LDS single buffer (A 16KB | B 16KB), 128 LDS
// rows x 8 XOR-swizzled chunks per operand (addressing verified in round 1:
// passed, 0 bank conflicts).
__global__ __launch_bounds__(256) void gemm0_mfma(
    const ushort* __restrict__ fh, const ushort* __restrict__ W0t,
    const float* __restrict__ combW, const int* __restrict__ species,
    ushort* __restrict__ h0f) {
  __shared__ ushort sh[16384];   // 32KB: A [0,8192) | B [8192,16384)
  int tid = threadIdx.x;
  int linear = blockIdx.y * 8 + blockIdx.x;
  int xc = linear & 7, sq = linear >> 3;
  int bm = ((sq >> 3) * 8 + xc) * 128;   // m-tile
  int bn = (sq & 7) * 128;               // n-tile
  int wid = tid >> 6, lane = tid & 63;
  int wm = (wid >> 1) * 64, wn = (wid & 1) * 64;

  // staging: unit u = j*256+tid -> LDS row r=u>>3 in [0,128), phys chunk u&7,
  // global k-chunk lc = (u&7) ^ (r&7). 4 units/thread per operand.
  const ushort* srcA[4];
  const ushort* srcB[4];
  int ldsu[4];
#pragma unroll
  for (int j = 0; j < 4; ++j) {
    int u = j * 256 + tid;
    int r = u >> 3;
    int lc = (u & 7) ^ (r & 7);
    srcA[j] = fh  + (size_t)(bm + r) * NF2 + lc * 8;
    srcB[j] = W0t + (size_t)(bn + r) * NF2 + lc * 8;
    ldsu[j] = u * 8;
  }

  f32x4 acc[4][4];
#pragma unroll
  for (int i = 0; i < 4; ++i)
#pragma unroll
    for (int j = 0; j < 4; ++j) acc[i][j] = (f32x4){0.f, 0.f, 0.f, 0.f};

  int mrow = lane & 15, qv = lane >> 4, h7 = mrow & 7;
  int pc0 = (qv ^ h7) * 8;               // phys chunk offset (ushorts), k-half 0
                                          // k-half 1: ^ 32 (chunk ^ 4)

  for (int k0 = 0; k0 < NF2; k0 += 64) {
#pragma unroll
    for (int j = 0; j < 4; ++j) {
      glds16(srcA[j] + k0, sh + ldsu[j]);
      glds16(srcB[j] + k0, sh + 8192 + ldsu[j]);
    }
    __syncthreads();
#pragma unroll
    for (int h = 0; h < 2; ++h) {
      int pc = pc0 ^ (h << 5);
      f16x8 af[4], bf[4];
#pragma unroll
      for (int i = 0; i < 4; ++i) {
        af[i] = *reinterpret_cast<const f16x8*>(&sh[(wm + i * 16 + mrow) * 64 + pc]);
        bf[i] = *reinterpret_cast<const f16x8*>(&sh[8192 + (wn + i * 16 + mrow) * 64 + pc]);
      }
#pragma unroll
      for (int i = 0; i < 4; ++i)
#pragma unroll
        for (int j = 0; j < 4; ++j)
          acc[i][j] = __builtin_amdgcn_mfma_f32_16x16x32_f16(af[i], bf[j], acc[i][j], 0, 0, 0);
    }
    __syncthreads();
  }

  int p = bn >> 8;
  int col = lane & 15, rbase = (lane >> 4) * 4;
#pragma unroll
  for (int i = 0; i < 4; ++i) {
#pragma unroll
    for (int r = 0; r < 4; ++r) {
      int m = bm + wm + i * 16 + rbase + r;
      bool live = (m < N_ATOMS);
      float pw = live ? combW[p * NS + species[m]] : 0.f;
#pragma unroll
      for (int j = 0; j < 4; ++j) {
        int n = bn + wn + j * 16 + col;
        float v = live ? silu(pw * acc[i][j][r]) : 0.f;
        h0f[(size_t)m * 1024 + n] = f2h(v);
      }
    }
  }
}

// ---------------- Kernel C: layer-1 MFMA, 64m x 256n(one p) per block ------
// (round-4 verified: per-ki breg prefetch + run-length sorted-sid atomics)
__global__ __launch_bounds__(256) void mlp1_mfma(
    const ushort* __restrict__ h0f, const ushort* __restrict__ W1t,
    const float* __restrict__ W2, const int* __restrict__ sid,
    float* __restrict__ out) {
  __shared__ ushort As[64 * 256];   // 32KB
  __shared__ float sout[NSTRUCT];
  int tid = threadIdx.x;
  int linear = blockIdx.x;                   // 0..639
  int xc = linear & 7, s = linear >> 3;      // s in [0,80)
  int p = s & 3, t = s >> 2;                 // t in [0,20)
  int bm = ((t >> 1) * 8 + xc) * 128 + (t & 1) * 64;   // 64-row tile
  int wid = tid >> 6, lane = tid & 63;
  int wn = wid * 64;                         // wave's n-quarter within p

  if (tid < NSTRUCT) sout[tid] = 0.f;

  int mrow = lane & 15;
  int qv = lane >> 4;
  int h7 = mrow & 7;

#pragma unroll
  for (int s8 = 0; s8 < 8; ++s8) {
    int d = s8 * 256 + tid;
    int r = d >> 5, pcs = d & 31;
    int lc = pcs ^ (r & 7);
    glds16(h0f + (size_t)(bm + r) * 1024 + p * 256 + lc * 8, As + d * 8);
  }

  const ushort* wb = W1t + (size_t)p * HID * HID;
  const ushort* wrow[4];
#pragma unroll
  for (int j = 0; j < 4; ++j)
    wrow[j] = wb + (size_t)(wn + j * 16 + mrow) * 256 + qv * 8;

  f16x8 bc[4], bn_[4];
#pragma unroll
  for (int j = 0; j < 4; ++j) bc[j] = *reinterpret_cast<const f16x8*>(wrow[j]);

  __syncthreads();   // drains glds16 + sout init visible

  f32x4 acc[4][4];
#pragma unroll
  for (int i = 0; i < 4; ++i)
#pragma unroll
    for (int j = 0; j < 4; ++j) acc[i][j] = (f32x4){0.f, 0.f, 0.f, 0.f};

#pragma unroll
  for (int ki = 0; ki < 8; ++ki) {
    if (ki < 7) {
#pragma unroll
      for (int j = 0; j < 4; ++j)
        bn_[j] = *reinterpret_cast<const f16x8*>(wrow[j] + (ki + 1) * 32);
    }
    f16x8 af[4];
#pragma unroll
    for (int i = 0; i < 4; ++i) {
      int row = i * 16 + mrow;
      int pc2 = (ki * 4 + qv) ^ h7;
      af[i] = *reinterpret_cast<const f16x8*>(&As[row * 256 + pc2 * 8]);
    }
#pragma unroll
    for (int i = 0; i < 4; ++i)
#pragma unroll
      for (int j = 0; j < 4; ++j)
        acc[i][j] = __builtin_amdgcn_mfma_f32_16x16x32_f16(af[i], bc[j], acc[i][j], 0, 0, 0);
    if (ki < 7) {
#pragma unroll
      for (int j = 0; j < 4; ++j) bc[j] = bn_[j];
    }
  }

  // fused layer-2 + segment-sum epilogue: run-length accumulate over sorted sid
  int col = lane & 15, quad = lane >> 4;
  float w2j[4];
#pragma unroll
  for (int j = 0; j < 4; ++j) w2j[j] = W2[p * 256 + wn + j * 16 + col];
  float runv = 0.f;
  int runs = -1;
#pragma unroll
  for (int i = 0; i < 4; ++i) {
#pragma unroll
    for (int r = 0; r < 4; ++r) {
      float v = silu(acc[i][0][r]) * w2j[0] + silu(acc[i][1][r]) * w2j[1]
              + silu(acc[i][2][r]) * w2j[2] + silu(acc[i][3][r]) * w2j[3];
      v += __shfl_xor(v, 1, 64);
      v += __shfl_xor(v, 2, 64);
      v += __shfl_xor(v, 4, 64);
      v += __shfl_xor(v, 8, 64);
      if (col == 0) {
        int m = bm + i * 16 + quad * 4 + r;       // strictly increasing in (i,r)
        int s_ = (m < N_ATOMS) ? sid[m] : -1;     // sorted, non-decreasing
        if (s_ != runs) {
          if (runs >= 0) atomicAdd(&sout[runs], runv);
          runs = s_;
          runv = 0.f;
        }
        if (s_ >= 0) runv += v;
      }
    }
  }
  if (col == 0 && runs >= 0) atomicAdd(&sout[runs], runv);

  __syncthreads();
  if (tid < NSTRUCT) {
    float v = sout[tid];
    if (v != 0.f) atomicAdd(&out[tid], v);
  }
}

extern "C" void kernel_launch(void* const* d_in, const int* in_sizes, int n_in,
                              void* d_out, int out_size, void* d_ws, size_t ws_size,
                              hipStream_t stream) {
  const float* c0      = (const float*)d_in[0];
  const float* c1      = (const float*)d_in[1];
  const float* c2      = (const float*)d_in[2];
  const float* c3      = (const float*)d_in[3];
  const int*   species = (const int*)d_in[4];
  const int*   sid     = (const int*)d_in[5];
  const float* combW   = (const float*)d_in[6];
  const float* W0      = (const float*)d_in[7];
  const float* W1      = (const float*)d_in[8];
  const float* W2      = (const float*)d_in[9];
  float*       out     = (float*)d_out;

  // ws: fh 52.4MB | W0t 5.2MB | W1t 0.5MB | h0f 21MB = ~79MB
  ushort* fh  = (ushort*)d_ws;
  ushort* W0t = fh  + (size_t)APAD * NF2;
  ushort* W1t = W0t + (size_t)NP * HID * NF2;
  ushort* h0f = W1t + (size_t)NP * HID * HID;

  prep_kernel<<<PB_TOTAL, 256, 0, stream>>>(c0, c1, c2, c3, W0, W1,
                                            fh, W0t, W1t, out);

  dim3 g2(8, APAD / 128);    // 8 n-tiles x 80 remapped slots
  gemm0_mfma<<<g2, 256, 0, stream>>>(fh, W0t, combW, species, h0f);

  mlp1_mfma<<<640, 256, 0, stream>>>(h0f, W1t, W2, sid, out);
}

// Round 10
// 202.387 us; speedup vs baseline: 1.2473x; 1.1010x over previous
//
#include <hip/hip_runtime.h>
#include <hip/hip_bf16.h>
#include <cstdint>
#include <cstddef>

#define N_ATOMS 10000
#define NSTRUCT 100
#define NP 4
#define NS 4
#define NF2 2560      // 4 l x 640 block-aligned symmetric-packed features
#define HID 256
#define APAD 10240    // 80 tiles of 128

// prep-kernel block ranges
#define PB_FEAT  2500                     // [0,2500): power spectrum, 4 atoms/block
#define PB_W0    (PB_FEAT + 2560)         // w0cvt: 8(n) x 80(k) x 4(p)
#define PB_W1    (PB_W0 + 256)            // w1cvt: 8 x 8 x 4
#define PB_ZERO  (PB_W1 + 300)            // fh tail rows 10000..10239
#define PB_TOTAL (PB_ZERO + 1)            // + out zero

typedef __attribute__((ext_vector_type(8))) _Float16 f16x8;
typedef __attribute__((ext_vector_type(8))) ushort u16x8;
typedef __attribute__((ext_vector_type(4))) float f32x4;

__device__ __forceinline__ float silu(float x) {
  return x / (1.f + __expf(-x));
}
__device__ __forceinline__ ushort f2h(float x) {
  _Float16 h = (_Float16)x;
  return *reinterpret_cast<ushort*>(&h);
}
// chunk c in [0,80) -> (row q, r-block b). Row q owns blocks q>>3 .. 3.
__device__ __forceinline__ void cdec(int c, int& q, int& b) {
  if (c < 32)      { q = c >> 2; b = c & 3; }
  else if (c < 56) { int x = c - 32; int j = (x * 171) >> 9; q = 8 + j; b = 1 + (x - j * 3); }
  else if (c < 72) { int x = c - 56; q = 16 + (x >> 1); b = 2 + (x & 1); }
  else             { q = 24 + (c - 72); b = 3; }
}

typedef __attribute__((address_space(3))) uint32_t lds_u32;
typedef const __attribute__((address_space(1))) uint32_t glb_u32;
__device__ __forceinline__ void glds16(const ushort* g, ushort* l) {
  __builtin_amdgcn_global_load_lds((glb_u32*)g, (lds_u32*)l, 16, 0, 0);
}

// ---------------- Kernel P: fused prep -------------------------------------
// round-4 structure; feat atom-loads vectorized to float4 (G13): the 512
// floats per atom = 128 float4s, loaded in 2 wave-rounds with <=2 uniform
// branch segments each (c0:8 | c1:24 | c2:40 | c3:56 f4-units, all 16B-
// aligned per atom). Replaces ~12 branchy scalar loads per lane.
__global__ __launch_bounds__(256) void prep_kernel(
    const float* __restrict__ c0, const float* __restrict__ c1,
    const float* __restrict__ c2, const float* __restrict__ c3,
    const float* __restrict__ W0, const float* __restrict__ W1,
    ushort* __restrict__ fh, ushort* __restrict__ W0t,
    ushort* __restrict__ W1t, float* __restrict__ out) {
  __shared__ float shbuf[2048];   // feat: 4 waves x 512; cvt: 32x33
  int b = blockIdx.x;
  int tid = threadIdx.x;

  if (b < PB_FEAT) {
    // ---- power spectrum, one WAVE per atom, 5 chunks/lane ----
    int wv = tid >> 6, lane = tid & 63;
    int a = b * 4 + wv;
    float* cs = shbuf + wv * 512;
    {
      const float4* s0 = reinterpret_cast<const float4*>(c0) + (size_t)a * 8;
      const float4* s1 = reinterpret_cast<const float4*>(c1) + (size_t)a * 24;
      const float4* s2 = reinterpret_cast<const float4*>(c2) + (size_t)a * 40;
      const float4* s3 = reinterpret_cast<const float4*>(c3) + (size_t)a * 56;
      float4* cs4 = reinterpret_cast<float4*>(cs);
      int f = lane;                 // round 0: f4 units [0,64)
      float4 v;
      if (f < 8)       v = s0[f];
      else if (f < 32) v = s1[f - 8];
      else             v = s2[f - 32];
      cs4[f] = v;
      int g = 64 + lane;            // round 1: f4 units [64,128)
      float4 w;
      if (g < 72)      w = s2[g - 32];
      else             w = s3[g - 72];
      cs4[g] = w;
    }
    __syncthreads();
    const float cg[4]  = {1.0f, 0.5773502691896258f, 0.4472135954999579f, 0.3779644730092272f};
    const int  off[4]  = {0, 32, 128, 288};
    const int  nm[4]   = {1, 3, 5, 7};
#pragma unroll
    for (int t = 0; t < 5; ++t) {
      int cc = lane + t * 64;           // [0,320), all lanes busy
      int l = cc / 80, c = cc - l * 80;
      int q, bb; cdec(c, q, bb);
      int rb = bb * 8;
      const float* base = cs + off[l];
      float s[8] = {0.f, 0.f, 0.f, 0.f, 0.f, 0.f, 0.f, 0.f};
      for (int m = 0; m < nm[l]; ++m) {
        float bq = base[m * 32 + q];
        float4 v0 = *reinterpret_cast<const float4*>(&base[m * 32 + rb]);
        float4 v1 = *reinterpret_cast<const float4*>(&base[m * 32 + rb + 4]);
        s[0] += bq * v0.x; s[1] += bq * v0.y; s[2] += bq * v0.z; s[3] += bq * v0.w;
        s[4] += bq * v1.x; s[5] += bq * v1.y; s[6] += bq * v1.z; s[7] += bq * v1.w;
      }
      u16x8 o;
#pragma unroll
      for (int u = 0; u < 8; ++u) o[u] = f2h(s[u] * cg[l]);
      *reinterpret_cast<u16x8*>(&fh[(size_t)a * NF2 + cc * 8]) = o;
    }
  } else if (b < PB_W0) {
    // ---- W0' fold -> W0t [p][h][fk] fp16 ----
    int idx = b - PB_FEAT;
    int nx = idx & 7;
    int rest = idx >> 3;
    int ky = rest % 80, p = rest / 80;
    int kt = ky * 32, nt = nx * 32;
    int lx = tid & 31, ly = tid >> 5;
    float (*t)[33] = (float(*)[33])shbuf;
    const float* src = W0 + (size_t)p * 4096 * HID;
#pragma unroll
    for (int i = 0; i < 4; ++i) {
      int kf = kt + ly + i * 8;
      int l = kf / 640, w = kf - l * 640;
      int c = w >> 3, s = w & 7;
      int q, bb; cdec(c, q, bb);
      int r = bb * 8 + s;
      float v = 0.f;
      if (r >= q) {
        v = src[(size_t)(l * 1024 + q * 32 + r) * HID + nt + lx];
        if (r > q) v += src[(size_t)(l * 1024 + r * 32 + q) * HID + nt + lx];
      }
      t[ly + i * 8][lx] = v;
    }
    __syncthreads();
    ushort* dst = W0t + (size_t)p * HID * NF2;
#pragma unroll
    for (int i = 0; i < 4; ++i)
      dst[(size_t)(nt + ly + i * 8) * NF2 + kt + lx] = f2h(t[lx][ly + i * 8]);
  } else if (b < PB_W1) {
    int idx = b - PB_W0;
    int nx = idx & 7, ky = (idx >> 3) & 7, p = idx >> 6;
    int kt = ky * 32, nt = nx * 32;
    int lx = tid & 31, ly = tid >> 5;
    float (*t)[33] = (float(*)[33])shbuf;
    const float* src = W1 + (size_t)p * HID * HID;
#pragma unroll
    for (int i = 0; i < 4; ++i)
      t[ly + i * 8][lx] = src[(size_t)(kt + ly + i * 8) * HID + nt + lx];
    __syncthreads();
    ushort* dst = W1t + (size_t)p * HID * HID;
#pragma unroll
    for (int i = 0; i < 4; ++i)
      dst[(size_t)(nt + ly + i * 8) * HID + kt + lx] = f2h(t[lx][ly + i * 8]);
  } else if (b < PB_ZERO) {
    int idx = b - PB_W1;
    size_t e = (size_t)idx * 2048 + tid * 8;
    u16x8 z = (u16x8){0, 0, 0, 0, 0, 0, 0, 0};
    *reinterpret_cast<u16x8*>(&fh[(size_t)N_ATOMS * NF2 + e]) = z;
  } else {
    if (tid < NSTRUCT) out[tid] = 0.f;
  }
}

// ---------------- Kernel B: fp16 MFMA GEMM0, 128x128, BK=32, K=2560 --------
// FROZEN at round-0 structure (82.6 us). Five structural variants (explicit
// pipelining x3, occupancy x2, LDS-bypass x2, BK=64) all regressed; this is
// the measured floor for this shape. Do not touch the inner loop.
__global__ __launch_bounds__(256) void gemm0_mfma(
    const ushort* __restrict__ fh, const ushort* __restrict__ W0t,
    const float* __restrict__ combW, const int* __restrict__ species,
    ushort* __restrict__ h0f) {
  __shared__ ushort As[64 * 64];   // 8KB
  __shared__ ushort Bs[64 * 64];   // 8KB
  int tid = threadIdx.x;
  int linear = blockIdx.y * 8 + blockIdx.x;
  int xc = linear & 7, sq = linear >> 3;
  int bm = ((sq >> 3) * 8 + xc) * 128;   // m-tile
  int bn = (sq & 7) * 128;               // n-tile
  int wid = tid >> 6, lane = tid & 63;
  int wm = (wid >> 1) * 64, wn = (wid & 1) * 64;
  int mh = wid >> 1, nh = wid & 1;

  int pr = tid >> 3, pc = tid & 7;
  int lg = pc ^ (pr & 7);
  int mhalf = lg >> 2, kc = lg & 3;
  const ushort* gaA1 = fh  + ((size_t)(bm + pr + 64 * mhalf) * NF2 + kc * 8);
  const ushort* gaA2 = gaA1 + (size_t)32 * NF2;
  const ushort* gaB1 = W0t + ((size_t)(bn + pr + 64 * mhalf) * NF2 + kc * 8);
  const ushort* gaB2 = gaB1 + (size_t)32 * NF2;
  ushort* lA = As + tid * 8;
  ushort* lB = Bs + tid * 8;

  f32x4 acc[4][4];
#pragma unroll
  for (int i = 0; i < 4; ++i)
#pragma unroll
    for (int j = 0; j < 4; ++j) acc[i][j] = (f32x4){0.f, 0.f, 0.f, 0.f};

  int mrow = lane & 15;
  int h7 = mrow & 7;
  int qv = lane >> 4;
  int pcA = ((mh << 2) | qv) ^ h7;
  int pcB = ((nh << 2) | qv) ^ h7;

  for (int k0 = 0; k0 < NF2; k0 += 32) {
    glds16(gaA1 + k0, lA);
    glds16(gaA2 + k0, lA + 2048);
    glds16(gaB1 + k0, lB);
    glds16(gaB2 + k0, lB + 2048);
    __syncthreads();

    f16x8 af[4], bf[4];
#pragma unroll
    for (int i = 0; i < 4; ++i) {
      af[i] = *reinterpret_cast<const f16x8*>(&As[(i * 16 + mrow) * 64 + pcA * 8]);
      bf[i] = *reinterpret_cast<const f16x8*>(&Bs[(i * 16 + mrow) * 64 + pcB * 8]);
    }
#pragma unroll
    for (int i = 0; i < 4; ++i)
#pragma unroll
      for (int j = 0; j < 4; ++j)
        acc[i][j] = __builtin_amdgcn_mfma_f32_16x16x32_f16(af[i], bf[j], acc[i][j], 0, 0, 0);
    __syncthreads();
  }

  int p = bn >> 8;
  int col = lane & 15, rbase = (lane >> 4) * 4;
#pragma unroll
  for (int i = 0; i < 4; ++i) {
#pragma unroll
    for (int r = 0; r < 4; ++r) {
      int m = bm + wm + i * 16 + rbase + r;
      bool live = (m < N_ATOMS);
      float pw = live ? combW[p * NS + species[m]] : 0.f;
#pragma unroll
      for (int j = 0; j < 4; ++j) {
        int n = bn + wn + j * 16 + col;
        float v = live ? silu(pw * acc[i][j][r]) : 0.f;
        h0f[(size_t)m * 1024 + n] = f2h(v);
      }
    }
  }
}

// ---------------- Kernel C: layer-1 MFMA, 64m x 256n(one p) per block ------
// (round-4 verified: per-ki breg prefetch + run-length sorted-sid atomics)
__global__ __launch_bounds__(256) void mlp1_mfma(
    const ushort* __restrict__ h0f, const ushort* __restrict__ W1t,
    const float* __restrict__ W2, const int* __restrict__ sid,
    float* __restrict__ out) {
  __shared__ ushort As[64 * 256];   // 32KB
  __shared__ float sout[NSTRUCT];
  int tid = threadIdx.x;
  int linear = blockIdx.x;                   // 0..639
  int xc = linear & 7, s = linear >> 3;      // s in [0,80)
  int p = s & 3, t = s >> 2;                 // t in [0,20)
  int bm = ((t >> 1) * 8 + xc) * 128 + (t & 1) * 64;   // 64-row tile
  int wid = tid >> 6, lane = tid & 63;
  int wn = wid * 64;                         // wave's n-quarter within p

  if (tid < NSTRUCT) sout[tid] = 0.f;

  int mrow = lane & 15;
  int qv = lane >> 4;
  int h7 = mrow & 7;

#pragma unroll
  for (int s8 = 0; s8 < 8; ++s8) {
    int d = s8 * 256 + tid;
    int r = d >> 5, pcs = d & 31;
    int lc = pcs ^ (r & 7);
    glds16(h0f + (size_t)(bm + r) * 1024 + p * 256 + lc * 8, As + d * 8);
  }

  const ushort* wb = W1t + (size_t)p * HID * HID;
  const ushort* wrow[4];
#pragma unroll
  for (int j = 0; j < 4; ++j)
    wrow[j] = wb + (size_t)(wn + j * 16 + mrow) * 256 + qv * 8;

  f16x8 bc[4], bn_[4];
#pragma unroll
  for (int j = 0; j < 4; ++j) bc[j] = *reinterpret_cast<const f16x8*>(wrow[j]);

  __syncthreads();   // drains glds16 + sout init visible

  f32x4 acc[4][4];
#pragma unroll
  for (int i = 0; i < 4; ++i)
#pragma unroll
    for (int j = 0; j < 4; ++j) acc[i][j] = (f32x4){0.f, 0.f, 0.f, 0.f};

#pragma unroll
  for (int ki = 0; ki < 8; ++ki) {
    if (ki < 7) {
#pragma unroll
      for (int j = 0; j < 4; ++j)
        bn_[j] = *reinterpret_cast<const f16x8*>(wrow[j] + (ki + 1) * 32);
    }
    f16x8 af[4];
#pragma unroll
    for (int i = 0; i < 4; ++i) {
      int row = i * 16 + mrow;
      int pc2 = (ki * 4 + qv) ^ h7;
      af[i] = *reinterpret_cast<const f16x8*>(&As[row * 256 + pc2 * 8]);
    }
#pragma unroll
    for (int i = 0; i < 4; ++i)
#pragma unroll
      for (int j = 0; j < 4; ++j)
        acc[i][j] = __builtin_amdgcn_mfma_f32_16x16x32_f16(af[i], bc[j], acc[i][j], 0, 0, 0);
    if (ki < 7) {
#pragma unroll
      for (int j = 0; j < 4; ++j) bc[j] = bn_[j];
    }
  }

  // fused layer-2 + segment-sum epilogue: run-length accumulate over sorted sid
  int col = lane & 15, quad = lane >> 4;
  float w2j[4];
#pragma unroll
  for (int j = 0; j < 4; ++j) w2j[j] = W2[p * 256 + wn + j * 16 + col];
  float runv = 0.f;
  int runs = -1;
#pragma unroll
  for (int i = 0; i < 4; ++i) {
#pragma unroll
    for (int r = 0; r < 4; ++r) {
      float v = silu(acc[i][0][r]) * w2j[0] + silu(acc[i][1][r]) * w2j[1]
              + silu(acc[i][2][r]) * w2j[2] + silu(acc[i][3][r]) * w2j[3];
      v += __shfl_xor(v, 1, 64);
      v += __shfl_xor(v, 2, 64);
      v += __shfl_xor(v, 4, 64);
      v += __shfl_xor(v, 8, 64);
      if (col == 0) {
        int m = bm + i * 16 + quad * 4 + r;       // strictly increasing in (i,r)
        int s_ = (m < N_ATOMS) ? sid[m] : -1;     // sorted, non-decreasing
        if (s_ != runs) {
          if (runs >= 0) atomicAdd(&sout[runs], runv);
          runs = s_;
          runv = 0.f;
        }
        if (s_ >= 0) runv += v;
      }
    }
  }
  if (col == 0 && runs >= 0) atomicAdd(&sout[runs], runv);

  __syncthreads();
  if (tid < NSTRUCT) {
    float v = sout[tid];
    if (v != 0.f) atomicAdd(&out[tid], v);
  }
}

extern "C" void kernel_launch(void* const* d_in, const int* in_sizes, int n_in,
                              void* d_out, int out_size, void* d_ws, size_t ws_size,
                              hipStream_t stream) {
  const float* c0      = (const float*)d_in[0];
  const float* c1      = (const float*)d_in[1];
  const float* c2      = (const float*)d_in[2];
  const float* c3      = (const float*)d_in[3];
  const int*   species = (const int*)d_in[4];
  const int*   sid     = (const int*)d_in[5];
  const float* combW   = (const float*)d_in[6];
  const float* W0      = (const float*)d_in[7];
  const float* W1      = (const float*)d_in[8];
  const float* W2      = (const float*)d_in[9];
  float*       out     = (float*)d_out;

  // ws: fh 52.4MB | W0t 5.2MB | W1t 0.5MB | h0f 21MB = ~79MB
  ushort* fh  = (ushort*)d_ws;
  ushort* W0t = fh  + (size_t)APAD * NF2;
  ushort* W1t = W0t + (size_t)NP * HID * NF2;
  ushort* h0f = W1t + (size_t)NP * HID * HID;

  prep_kernel<<<PB_TOTAL, 256, 0, stream>>>(c0, c1, c2, c3, W0, W1,
                                            fh, W0t, W1t, out);

  dim3 g2(8, APAD / 128);    // 8 n-tiles x 80 remapped slots
  gemm0_mfma<<<g2, 256, 0, stream>>>(fh, W0t, combW, species, h0f);

  mlp1_mfma<<<640, 256, 0, stream>>>(h0f, W1t, W2, sid, out);
}

// Round 11
// 202.307 us; speedup vs baseline: 1.2478x; 1.0004x over previous
//
#include <hip/hip_runtime.h>
#include <hip/hip_bf16.h>
#include <cstdint>
#include <cstddef>

#define N_ATOMS 10000
#define NSTRUCT 100
#define NP 4
#define NS 4
#define NF2 2560      // 4 l x 640 block-aligned symmetric-packed features
#define HID 256
#define APAD 10240    // 80 tiles of 128

// prep-kernel block ranges
#define PB_FEAT  2500                     // [0,2500): power spectrum, 4 atoms/block
#define PB_W0    (PB_FEAT + 2560)         // w0cvt: 8(n) x 80(k) x 4(p)
#define PB_W1    (PB_W0 + 256)            // w1cvt: 8 x 8 x 4
#define PB_ZERO  (PB_W1 + 300)            // fh tail rows 10000..10239
#define PB_TOTAL (PB_ZERO + 1)            // + out zero

typedef __attribute__((ext_vector_type(8))) _Float16 f16x8;
typedef __attribute__((ext_vector_type(8))) ushort u16x8;
typedef __attribute__((ext_vector_type(4))) float f32x4;

__device__ __forceinline__ float silu(float x) {
  return x / (1.f + __expf(-x));
}
__device__ __forceinline__ ushort f2h(float x) {
  _Float16 h = (_Float16)x;
  return *reinterpret_cast<ushort*>(&h);
}
// chunk c in [0,80) -> (row q, r-block b). Row q owns blocks q>>3 .. 3.
__device__ __forceinline__ void cdec(int c, int& q, int& b) {
  if (c < 32)      { q = c >> 2; b = c & 3; }
  else if (c < 56) { int x = c - 32; int j = (x * 171) >> 9; q = 8 + j; b = 1 + (x - j * 3); }
  else if (c < 72) { int x = c - 56; q = 16 + (x >> 1); b = 2 + (x & 1); }
  else             { q = 24 + (c - 72); b = 3; }
}

typedef __attribute__((address_space(3))) uint32_t lds_u32;
typedef const __attribute__((address_space(1))) uint32_t glb_u32;
__device__ __forceinline__ void glds16(const ushort* g, ushort* l) {
  __builtin_amdgcn_global_load_lds((glb_u32*)g, (lds_u32*)l, 16, 0, 0);
}

// ---------------- Kernel P: fused prep (round-4 verbatim; champion) --------
// NOTE: float4 feat-loader variant (r10) measured -6us vs this scalar loop;
// reverted. Do not re-vectorize without within-probe A/B.
__global__ __launch_bounds__(256) void prep_kernel(
    const float* __restrict__ c0, const float* __restrict__ c1,
    const float* __restrict__ c2, const float* __restrict__ c3,
    const float* __restrict__ W0, const float* __restrict__ W1,
    ushort* __restrict__ fh, ushort* __restrict__ W0t,
    ushort* __restrict__ W1t, float* __restrict__ out) {
  __shared__ float shbuf[2048];   // feat: 4 waves x 512; cvt: 32x33
  int b = blockIdx.x;
  int tid = threadIdx.x;

  if (b < PB_FEAT) {
    // ---- power spectrum, one WAVE per atom, 5 chunks/lane ----
    int wv = tid >> 6, lane = tid & 63;
    int a = b * 4 + wv;
    float* cs = shbuf + wv * 512;
    for (int i = 0; i < 8; ++i) {
      int e = lane + i * 64;
      float v;
      if (e < 32)       v = c0[a * 32  + e];
      else if (e < 128) v = c1[a * 96  + (e - 32)];
      else if (e < 288) v = c2[a * 160 + (e - 128)];
      else              v = c3[a * 224 + (e - 288)];
      cs[e] = v;
    }
    __syncthreads();
    const float cg[4]  = {1.0f, 0.5773502691896258f, 0.4472135954999579f, 0.3779644730092272f};
    const int  off[4]  = {0, 32, 128, 288};
    const int  nm[4]   = {1, 3, 5, 7};
#pragma unroll
    for (int t = 0; t < 5; ++t) {
      int cc = lane + t * 64;           // [0,320), all lanes busy
      int l = cc / 80, c = cc - l * 80;
      int q, bb; cdec(c, q, bb);
      int rb = bb * 8;
      const float* base = cs + off[l];
      float s[8] = {0.f, 0.f, 0.f, 0.f, 0.f, 0.f, 0.f, 0.f};
      for (int m = 0; m < nm[l]; ++m) {
        float bq = base[m * 32 + q];
        float4 v0 = *reinterpret_cast<const float4*>(&base[m * 32 + rb]);
        float4 v1 = *reinterpret_cast<const float4*>(&base[m * 32 + rb + 4]);
        s[0] += bq * v0.x; s[1] += bq * v0.y; s[2] += bq * v0.z; s[3] += bq * v0.w;
        s[4] += bq * v1.x; s[5] += bq * v1.y; s[6] += bq * v1.z; s[7] += bq * v1.w;
      }
      u16x8 o;
#pragma unroll
      for (int u = 0; u < 8; ++u) o[u] = f2h(s[u] * cg[l]);
      *reinterpret_cast<u16x8*>(&fh[(size_t)a * NF2 + cc * 8]) = o;
    }
  } else if (b < PB_W0) {
    // ---- W0' fold -> W0t [p][h][fk] fp16 ----
    int idx = b - PB_FEAT;
    int nx = idx & 7;
    int rest = idx >> 3;
    int ky = rest % 80, p = rest / 80;
    int kt = ky * 32, nt = nx * 32;
    int lx = tid & 31, ly = tid >> 5;
    float (*t)[33] = (float(*)[33])shbuf;
    const float* src = W0 + (size_t)p * 4096 * HID;
#pragma unroll
    for (int i = 0; i < 4; ++i) {
      int kf = kt + ly + i * 8;
      int l = kf / 640, w = kf - l * 640;
      int c = w >> 3, s = w & 7;
      int q, bb; cdec(c, q, bb);
      int r = bb * 8 + s;
      float v = 0.f;
      if (r >= q) {
        v = src[(size_t)(l * 1024 + q * 32 + r) * HID + nt + lx];
        if (r > q) v += src[(size_t)(l * 1024 + r * 32 + q) * HID + nt + lx];
      }
      t[ly + i * 8][lx] = v;
    }
    __syncthreads();
    ushort* dst = W0t + (size_t)p * HID * NF2;
#pragma unroll
    for (int i = 0; i < 4; ++i)
      dst[(size_t)(nt + ly + i * 8) * NF2 + kt + lx] = f2h(t[lx][ly + i * 8]);
  } else if (b < PB_W1) {
    int idx = b - PB_W0;
    int nx = idx & 7, ky = (idx >> 3) & 7, p = idx >> 6;
    int kt = ky * 32, nt = nx * 32;
    int lx = tid & 31, ly = tid >> 5;
    float (*t)[33] = (float(*)[33])shbuf;
    const float* src = W1 + (size_t)p * HID * HID;
#pragma unroll
    for (int i = 0; i < 4; ++i)
      t[ly + i * 8][lx] = src[(size_t)(kt + ly + i * 8) * HID + nt + lx];
    __syncthreads();
    ushort* dst = W1t + (size_t)p * HID * HID;
#pragma unroll
    for (int i = 0; i < 4; ++i)
      dst[(size_t)(nt + ly + i * 8) * HID + kt + lx] = f2h(t[lx][ly + i * 8]);
  } else if (b < PB_ZERO) {
    int idx = b - PB_W1;
    size_t e = (size_t)idx * 2048 + tid * 8;
    u16x8 z = (u16x8){0, 0, 0, 0, 0, 0, 0, 0};
    *reinterpret_cast<u16x8*>(&fh[(size_t)N_ATOMS * NF2 + e]) = z;
  } else {
    if (tid < NSTRUCT) out[tid] = 0.f;
  }
}

// ---------------- Kernel B: fp16 MFMA GEMM0, 128x128, BK=32, K=2560 --------
// FROZEN at round-0 structure (82.6 us measured floor). Refuted variants:
// dbuf BK=64 (r1), counted-vmcnt pipeline (r2), 3-deep pipeline (r3),
// 64x128 occupancy 2x (r5), direct-global fragments (r6), B-from-global
// fragment-major (r7), single-buffer BK=64 (r9), fused with mlp1 (r8).
__global__ __launch_bounds__(256) void gemm0_mfma(
    const ushort* __restrict__ fh, const ushort* __restrict__ W0t,
    const float* __restrict__ combW, const int* __restrict__ species,
    ushort* __restrict__ h0f) {
  __shared__ ushort As[64 * 64];   // 8KB
  __shared__ ushort Bs[64 * 64];   // 8KB
  int tid = threadIdx.x;
  int linear = blockIdx.y * 8 + blockIdx.x;
  int xc = linear & 7, sq = linear >> 3;
  int bm = ((sq >> 3) * 8 + xc) * 128;   // m-tile
  int bn = (sq & 7) * 128;               // n-tile
  int wid = tid >> 6, lane = tid & 63;
  int wm = (wid >> 1) * 64, wn = (wid & 1) * 64;
  int mh = wid >> 1, nh = wid & 1;

  int pr = tid >> 3, pc = tid & 7;
  int lg = pc ^ (pr & 7);
  int mhalf = lg >> 2, kc = lg & 3;
  const ushort* gaA1 = fh  + ((size_t)(bm + pr + 64 * mhalf) * NF2 + kc * 8);
  const ushort* gaA2 = gaA1 + (size_t)32 * NF2;
  const ushort* gaB1 = W0t + ((size_t)(bn + pr + 64 * mhalf) * NF2 + kc * 8);
  const ushort* gaB2 = gaB1 + (size_t)32 * NF2;
  ushort* lA = As + tid * 8;
  ushort* lB = Bs + tid * 8;

  f32x4 acc[4][4];
#pragma unroll
  for (int i = 0; i < 4; ++i)
#pragma unroll
    for (int j = 0; j < 4; ++j) acc[i][j] = (f32x4){0.f, 0.f, 0.f, 0.f};

  int mrow = lane & 15;
  int h7 = mrow & 7;
  int qv = lane >> 4;
  int pcA = ((mh << 2) | qv) ^ h7;
  int pcB = ((nh << 2) | qv) ^ h7;

  for (int k0 = 0; k0 < NF2; k0 += 32) {
    glds16(gaA1 + k0, lA);
    glds16(gaA2 + k0, lA + 2048);
    glds16(gaB1 + k0, lB);
    glds16(gaB2 + k0, lB + 2048);
    __syncthreads();

    f16x8 af[4], bf[4];
#pragma unroll
    for (int i = 0; i < 4; ++i) {
      af[i] = *reinterpret_cast<const f16x8*>(&As[(i * 16 + mrow) * 64 + pcA * 8]);
      bf[i] = *reinterpret_cast<const f16x8*>(&Bs[(i * 16 + mrow) * 64 + pcB * 8]);
    }
#pragma unroll
    for (int i = 0; i < 4; ++i)
#pragma unroll
      for (int j = 0; j < 4; ++j)
        acc[i][j] = __builtin_amdgcn_mfma_f32_16x16x32_f16(af[i], bf[j], acc[i][j], 0, 0, 0);
    __syncthreads();
  }

  int p = bn >> 8;
  int col = lane & 15, rbase = (lane >> 4) * 4;
#pragma unroll
  for (int i = 0; i < 4; ++i) {
#pragma unroll
    for (int r = 0; r < 4; ++r) {
      int m = bm + wm + i * 16 + rbase + r;
      bool live = (m < N_ATOMS);
      float pw = live ? combW[p * NS + species[m]] : 0.f;
#pragma unroll
      for (int j = 0; j < 4; ++j) {
        int n = bn + wn + j * 16 + col;
        float v = live ? silu(pw * acc[i][j][r]) : 0.f;
        h0f[(size_t)m * 1024 + n] = f2h(v);
      }
    }
  }
}

// ---------------- Kernel C: layer-1 MFMA, 64m x 256n(one p) per block ------
// (round-4 verified: per-ki breg prefetch + run-length sorted-sid atomics)
__global__ __launch_bounds__(256) void mlp1_mfma(
    const ushort* __restrict__ h0f, const ushort* __restrict__ W1t,
    const float* __restrict__ W2, const int* __restrict__ sid,
    float* __restrict__ out) {
  __shared__ ushort As[64 * 256];   // 32KB
  __shared__ float sout[NSTRUCT];
  int tid = threadIdx.x;
  int linear = blockIdx.x;                   // 0..639
  int xc = linear & 7, s = linear >> 3;      // s in [0,80)
  int p = s & 3, t = s >> 2;                 // t in [0,20)
  int bm = ((t >> 1) * 8 + xc) * 128 + (t & 1) * 64;   // 64-row tile
  int wid = tid >> 6, lane = tid & 63;
  int wn = wid * 64;                         // wave's n-quarter within p

  if (tid < NSTRUCT) sout[tid] = 0.f;

  int mrow = lane & 15;
  int qv = lane >> 4;
  int h7 = mrow & 7;

#pragma unroll
  for (int s8 = 0; s8 < 8; ++s8) {
    int d = s8 * 256 + tid;
    int r = d >> 5, pcs = d & 31;
    int lc = pcs ^ (r & 7);
    glds16(h0f + (size_t)(bm + r) * 1024 + p * 256 + lc * 8, As + d * 8);
  }

  const ushort* wb = W1t + (size_t)p * HID * HID;
  const ushort* wrow[4];
#pragma unroll
  for (int j = 0; j < 4; ++j)
    wrow[j] = wb + (size_t)(wn + j * 16 + mrow) * 256 + qv * 8;

  f16x8 bc[4], bn_[4];
#pragma unroll
  for (int j = 0; j < 4; ++j) bc[j] = *reinterpret_cast<const f16x8*>(wrow[j]);

  __syncthreads();   // drains glds16 + sout init visible

  f32x4 acc[4][4];
#pragma unroll
  for (int i = 0; i < 4; ++i)
#pragma unroll
    for (int j = 0; j < 4; ++j) acc[i][j] = (f32x4){0.f, 0.f, 0.f, 0.f};

#pragma unroll
  for (int ki = 0; ki < 8; ++ki) {
    if (ki < 7) {
#pragma unroll
      for (int j = 0; j < 4; ++j)
        bn_[j] = *reinterpret_cast<const f16x8*>(wrow[j] + (ki + 1) * 32);
    }
    f16x8 af[4];
#pragma unroll
    for (int i = 0; i < 4; ++i) {
      int row = i * 16 + mrow;
      int pc2 = (ki * 4 + qv) ^ h7;
      af[i] = *reinterpret_cast<const f16x8*>(&As[row * 256 + pc2 * 8]);
    }
#pragma unroll
    for (int i = 0; i < 4; ++i)
#pragma unroll
      for (int j = 0; j < 4; ++j)
        acc[i][j] = __builtin_amdgcn_mfma_f32_16x16x32_f16(af[i], bc[j], acc[i][j], 0, 0, 0);
    if (ki < 7) {
#pragma unroll
      for (int j = 0; j < 4; ++j) bc[j] = bn_[j];
    }
  }

  // fused layer-2 + segment-sum epilogue: run-length accumulate over sorted sid
  int col = lane & 15, quad = lane >> 4;
  float w2j[4];
#pragma unroll
  for (int j = 0; j < 4; ++j) w2j[j] = W2[p * 256 + wn + j * 16 + col];
  float runv = 0.f;
  int runs = -1;
#pragma unroll
  for (int i = 0; i < 4; ++i) {
#pragma unroll
    for (int r = 0; r < 4; ++r) {
      float v = silu(acc[i][0][r]) * w2j[0] + silu(acc[i][1][r]) * w2j[1]
              + silu(acc[i][2][r]) * w2j[2] + silu(acc[i][3][r]) * w2j[3];
      v += __shfl_xor(v, 1, 64);
      v += __shfl_xor(v, 2, 64);
      v += __shfl_xor(v, 4, 64);
      v += __shfl_xor(v, 8, 64);
      if (col == 0) {
        int m = bm + i * 16 + quad * 4 + r;       // strictly increasing in (i,r)
        int s_ = (m < N_ATOMS) ? sid[m] : -1;     // sorted, non-decreasing
        if (s_ != runs) {
          if (runs >= 0) atomicAdd(&sout[runs], runv);
          runs = s_;
          runv = 0.f;
        }
        if (s_ >= 0) runv += v;
      }
    }
  }
  if (col == 0 && runs >= 0) atomicAdd(&sout[runs], runv);

  __syncthreads();
  if (tid < NSTRUCT) {
    float v = sout[tid];
    if (v != 0.f) atomicAdd(&out[tid], v);
  }
}

extern "C" void kernel_launch(void* const* d_in, const int* in_sizes, int n_in,
                              void* d_out, int out_size, void* d_ws, size_t ws_size,
                              hipStream_t stream) {
  const float* c0      = (const float*)d_in[0];
  const float* c1      = (const float*)d_in[1];
  const float* c2      = (const float*)d_in[2];
  const float* c3      = (const float*)d_in[3];
  const int*   species = (const int*)d_in[4];
  const int*   sid     = (const int*)d_in[5];
  const float* combW   = (const float*)d_in[6];
  const float* W0      = (const float*)d_in[7];
  const float* W1      = (const float*)d_in[8];
  const float* W2      = (const float*)d_in[9];
  float*       out     = (float*)d_out;

  // ws: fh 52.4MB | W0t 5.2MB | W1t 0.5MB | h0f 21MB = ~79MB
  ushort* fh  = (ushort*)d_ws;
  ushort* W0t = fh  + (size_t)APAD * NF2;
  ushort* W1t = W0t + (size_t)NP * HID * NF2;
  ushort* h0f = W1t + (size_t)NP * HID * HID;

  prep_kernel<<<PB_TOTAL, 256, 0, stream>>>(c0, c1, c2, c3, W0, W1,
                                            fh, W0t, W1t, out);

  dim3 g2(8, APAD / 128);    // 8 n-tiles x 80 remapped slots
  gemm0_mfma<<<g2, 256, 0, stream>>>(fh, W0t, combW, species, h0f);

  mlp1_mfma<<<640, 256, 0, stream>>>(h0f, W1t, W2, sid, out);
}